// Round 10
// baseline (231.093 us; speedup 1.0000x reference)
//
#include <hip/hip_runtime.h>

#define HEADS 16
#define HD 64
#define DM 1024
#define LSEQ 4096
#define NEGF (-1.0e30f)

typedef __attribute__((ext_vector_type(8))) short bf16x8;
typedef __attribute__((ext_vector_type(4))) float f32x4;
typedef unsigned short u16;

#define MFMA16(a, b, c) __builtin_amdgcn_mfma_f32_16x16x32_bf16((a), (b), (c), 0, 0, 0)

static __device__ __forceinline__ float b2f(u16 u) {
  union { float f; unsigned i; } t; t.i = ((unsigned)u) << 16; return t.f;
}
static __device__ __forceinline__ u16 f2b(float f) {
  union { float f; unsigned i; } t; t.f = f;
  unsigned r = t.i + 0x7fffu + ((t.i >> 16) & 1u);
  return (u16)(r >> 16);
}
static __device__ __forceinline__ ushort4 pk4(float4 v) {
  return make_ushort4(f2b(v.x), f2b(v.y), f2b(v.z), f2b(v.w));
}
static __device__ __forceinline__ void gload16(const void* g, void* l) {
  __builtin_amdgcn_global_load_lds((const __attribute__((address_space(1))) void*)g,
                                   (__attribute__((address_space(3))) void*)l, 16, 0, 0);
}

// ---------------- rope tables: cos/sin for window positions 0..511, dims 0..63 ----
__global__ void rope_build(float* __restrict__ ropc, float* __restrict__ rops) {
  int p = blockIdx.x, d = threadIdx.x;
  int t2 = d & ~1;
  double inv = pow(10000.0, -(double)t2 / 64.0);
  double f = (double)p * inv;
  ropc[p * 64 + d] = (float)cos(f);
  rops[p * 64 + d] = (float)sin(f);
}

// ---------------- weights f32 -> bf16 (4 at once) ----------------
__global__ void cvtw(const float4* __restrict__ a, const float4* __restrict__ b,
                     const float4* __restrict__ c, const float4* __restrict__ d,
                     ushort4* __restrict__ out) {
  int i = blockIdx.x * blockDim.x + threadIdx.x;  // 0..262143 (float4 units of 1M elems)
  out[i]          = pk4(a[i]);
  out[i + 262144] = pk4(b[i]);
  out[i + 524288] = pk4(c[i]);
  out[i + 786432] = pk4(d[i]);
}

// ---------------- fused LayerNorm for q,k,v (f32 in, bf16 out) --------------------
__global__ __launch_bounds__(256) void ln_qkv(
    const float4* __restrict__ q, const float4* __restrict__ k, const float4* __restrict__ v,
    const float* __restrict__ g0, const float* __restrict__ b0,
    const float* __restrict__ g1, const float* __restrict__ b1,
    const float* __restrict__ g2, const float* __restrict__ b2,
    ushort4* __restrict__ o0, ushort4* __restrict__ o1, ushort4* __restrict__ o2) {
  const int row = blockIdx.x, tid = threadIdx.x, sel = blockIdx.y;
  const float4* src = (sel == 0) ? q : (sel == 1) ? k : v;
  const float* gam = (sel == 0) ? g0 : (sel == 1) ? g1 : g2;
  const float* bet = (sel == 0) ? b0 : (sel == 1) ? b1 : b2;
  ushort4* dst = (sel == 0) ? o0 : (sel == 1) ? o1 : o2;

  float4 v4 = src[(size_t)row * 256 + tid];
  float s = v4.x + v4.y + v4.z + v4.w;
  float s2 = v4.x * v4.x + v4.y * v4.y + v4.z * v4.z + v4.w * v4.w;
#pragma unroll
  for (int d = 1; d < 64; d <<= 1) { s += __shfl_xor(s, d); s2 += __shfl_xor(s2, d); }
  __shared__ float ps[8];
  int lane = tid & 63, wave = tid >> 6;
  if (lane == 0) { ps[wave] = s; ps[4 + wave] = s2; }
  __syncthreads();
  float tot = ps[0] + ps[1] + ps[2] + ps[3];
  float tot2 = ps[4] + ps[5] + ps[6] + ps[7];
  float mean = tot * (1.f / 1024.f);
  float var = tot2 * (1.f / 1024.f) - mean * mean;
  float rstd = rsqrtf(var + 1e-5f);
  float4 gv = ((const float4*)gam)[tid];
  float4 bv = ((const float4*)bet)[tid];
  dst[(size_t)row * 256 + tid] = make_ushort4(
      f2b((v4.x - mean) * rstd * gv.x + bv.x), f2b((v4.y - mean) * rstd * gv.y + bv.y),
      f2b((v4.z - mean) * rstd * gv.z + bv.z), f2b((v4.w - mean) * rstd * gv.w + bv.w));
}

// ---------------- LayerNorm rows (bf16 in, bf16 out) — for O projection -----------
__global__ __launch_bounds__(256) void ln_rows(const ushort4* __restrict__ xin,
                                               const float* __restrict__ gam,
                                               const float* __restrict__ bet,
                                               ushort4* __restrict__ out) {
  int row = blockIdx.x, tid = threadIdx.x;
  ushort4 u = xin[(size_t)row * 256 + tid];
  float4 v;
  v.x = b2f(u.x); v.y = b2f(u.y); v.z = b2f(u.z); v.w = b2f(u.w);
  float s = v.x + v.y + v.z + v.w;
  float s2 = v.x * v.x + v.y * v.y + v.z * v.z + v.w * v.w;
#pragma unroll
  for (int d = 1; d < 64; d <<= 1) { s += __shfl_xor(s, d); s2 += __shfl_xor(s2, d); }
  __shared__ float ps[8];
  int lane = tid & 63, wave = tid >> 6;
  if (lane == 0) { ps[wave] = s; ps[4 + wave] = s2; }
  __syncthreads();
  float tot = ps[0] + ps[1] + ps[2] + ps[3];
  float tot2 = ps[4] + ps[5] + ps[6] + ps[7];
  float mean = tot * (1.f / 1024.f);
  float var = tot2 * (1.f / 1024.f) - mean * mean;
  float rstd = rsqrtf(var + 1e-5f);
  float4 gv = ((const float4*)gam)[tid];
  float4 bv = ((const float4*)bet)[tid];
  out[(size_t)row * 256 + tid] = make_ushort4(
      f2b((v.x - mean) * rstd * gv.x + bv.x), f2b((v.y - mean) * rstd * gv.y + bv.y),
      f2b((v.z - mean) * rstd * gv.z + bv.z), f2b((v.w - mean) * rstd * gv.w + bv.w));
}

// ---------------- fused QKV NT GEMM (blockIdx.y = mode 0/1/2) ---------------------
// mode 0 = Q (scaled 0.125, rotary pos=l%256 -> qrot BHLd)
// mode 1 = K (rotary pos=256+l%256 -> krot BHLd; single view — prev view derived in attn)
// mode 2 = V (bf16 transposed BHdL -> vT)
// Epilogue stages C through LDS (overlaying Als/Bls) -> 16B coalesced stores.
__global__ __launch_bounds__(256, 3) void gemm_qkv(
    const u16* __restrict__ Aq, const u16* __restrict__ Ak, const u16* __restrict__ Av,
    const u16* __restrict__ wbf,
    const float* __restrict__ bq, const float* __restrict__ bk, const float* __restrict__ bv,
    const float* __restrict__ ropc, const float* __restrict__ rops,
    u16* __restrict__ qrot, u16* __restrict__ krot, u16* __restrict__ vTp) {
  __shared__ __align__(16) char smem[34816];  // staging 32KB; epilogue C-tile 128x136 u16
  u16* Als = (u16*)smem;
  u16* Bls = (u16*)(smem + 16384);
  const int tid = threadIdx.x, lane = tid & 63, wave = tid >> 6;
  const int g = lane >> 4, ln15 = lane & 15;
  const int mode = blockIdx.y;
  const u16* A = (mode == 0) ? Aq : (mode == 1) ? Ak : Av;
  const u16* Bw = wbf + (size_t)mode * 1048576;
  const float* bias = (mode == 0) ? bq : (mode == 1) ? bk : bv;
  // XCD-chunked swizzle on x (bijective; 512 blocks, 64 M-tiles x 8 N-tiles)
  const int bid = blockIdx.x;
  const int xcd = bid & 7, idx = bid >> 3;
  const int row0 = (xcd * 8 + (idx >> 3)) * 128;
  const int col0 = (idx & 7) * 128;
  const int wm = (wave >> 1) * 64, wn = (wave & 1) * 64;
  const int K = 1024;
  f32x4 acc[4][4] = {};

  for (int k0 = 0; k0 < K; k0 += 64) {
#pragma unroll
    for (int i = 0; i < 4; ++i) {  // A tile: 16KB, swizzled via pre-swizzled source
      int ch = i * 4 + wave;
      int olin = ch * 1024 + lane * 16;
      int r = olin >> 7;
      int cel = ((olin ^ ((r & 7) << 4)) >> 1) & 63;
      gload16(A + (size_t)(row0 + r) * K + k0 + cel, (char*)Als + ch * 1024);
    }
#pragma unroll
    for (int i = 0; i < 4; ++i) {  // B tile
      int ch = i * 4 + wave;
      int olin = ch * 1024 + lane * 16;
      int r = olin >> 7;
      int cel = ((olin ^ ((r & 7) << 4)) >> 1) & 63;
      gload16(Bw + (size_t)(col0 + r) * K + k0 + cel, (char*)Bls + ch * 1024);
    }
    __syncthreads();
#pragma unroll
    for (int ks = 0; ks < 2; ++ks) {
      bf16x8 af[4], bfv[4];
      int cb = (ks * 32 + g * 8) * 2;
#pragma unroll
      for (int mi = 0; mi < 4; ++mi) {
        int r = wm + mi * 16 + ln15;
        af[mi] = *(const bf16x8*)((const char*)Als + r * 128 + (cb ^ ((r & 7) << 4)));
      }
#pragma unroll
      for (int ni = 0; ni < 4; ++ni) {
        int r = wn + ni * 16 + ln15;
        bfv[ni] = *(const bf16x8*)((const char*)Bls + r * 128 + (cb ^ ((r & 7) << 4)));
      }
#pragma unroll
      for (int mi = 0; mi < 4; ++mi)
#pragma unroll
        for (int ni = 0; ni < 4; ++ni)
          acc[mi][ni] = MFMA16(af[mi], bfv[ni], acc[mi][ni]);
    }
    __syncthreads();
  }

  // ---- epilogue: rotary (f32, single rounding) + LDS-staged coalesced writes ----
  u16* Cl = (u16*)smem;  // 128 x 136 u16 (stride 272B: 16B-aligned rows, bank-spread)
#pragma unroll
  for (int mi = 0; mi < 4; ++mi)
#pragma unroll
    for (int ni = 0; ni < 4; ++ni)
#pragma unroll
      for (int r = 0; r < 4; ++r) {
        int rowc = wm + mi * 16 + g * 4 + r;
        int colc = wn + ni * 16 + ln15;
        int row = row0 + rowc, col = col0 + colc;
        float val = acc[mi][ni][r] + bias[col];
        if (mode == 2) {
          Cl[colc * 136 + rowc] = f2b(val);  // transposed store for (B,H,d,L) out
        } else {
          if (mode == 0) val *= 0.125f;      // fold 1/sqrt(hd) into Q
          float oth = __shfl_xor(val, 1);    // rotary partner (adjacent dim = adjacent lane)
          int d = col & 63;
          int pp = (row & 255) + ((mode == 1) ? 256 : 0);
          float cc = ropc[pp * 64 + d], ss = rops[pp * 64 + d];
          Cl[rowc * 136 + colc] = f2b((d & 1) ? (val * cc + oth * ss) : (val * cc - oth * ss));
        }
      }
  __syncthreads();
  if (mode == 2) {
#pragma unroll
    for (int i = 0; i < 8; ++i) {
      int c2 = i * 256 + tid;
      int dloc = c2 >> 4, lgrp = c2 & 15;
      bf16x8 vv = *(const bf16x8*)(Cl + dloc * 136 + lgrp * 8);
      int colg = col0 + dloc, hh = colg >> 6, d = colg & 63;
      int l = row0 + lgrp * 8, bb = l >> 12, ll = l & 4095;
      *(bf16x8*)(vTp + (((size_t)bb * HEADS + hh) * HD + d) * LSEQ + ll) = vv;
    }
  } else {
    u16* dst = (mode == 0) ? qrot : krot;
#pragma unroll
    for (int i = 0; i < 8; ++i) {
      int c2 = i * 256 + tid;
      int rowc = c2 >> 4, cgrp = c2 & 15;
      bf16x8 vv = *(const bf16x8*)(Cl + rowc * 136 + cgrp * 8);
      int l = row0 + rowc, bb = l >> 12, ll = l & 4095;
      int colg = col0 + cgrp * 8, hh = colg >> 6, d0 = colg & 63;
      *(bf16x8*)(dst + (((size_t)bb * HEADS + hh) * LSEQ + ll) * HD + d0) = vv;
    }
  }
}

// ---------------- final NT GEMM: out = LN(o) @ Wo^T + bias (f32) ------------------
__global__ __launch_bounds__(256, 3) void gemm_o(
    const u16* __restrict__ A, const u16* __restrict__ Bw, const float* __restrict__ bias,
    float* __restrict__ outf) {
  __shared__ __align__(16) u16 Als[128 * 64];
  __shared__ __align__(16) u16 Bls[128 * 64];
  const int tid = threadIdx.x, lane = tid & 63, wave = tid >> 6;
  const int g = lane >> 4, ln15 = lane & 15;
  const int bid = blockIdx.x;
  const int xcd = bid & 7, idx = bid >> 3;
  const int row0 = (xcd * 8 + (idx >> 3)) * 128;
  const int col0 = (idx & 7) * 128;
  const int wm = (wave >> 1) * 64, wn = (wave & 1) * 64;
  const int K = 1024, N = 1024;
  f32x4 acc[4][4] = {};

  for (int k0 = 0; k0 < K; k0 += 64) {
#pragma unroll
    for (int i = 0; i < 4; ++i) {
      int ch = i * 4 + wave;
      int olin = ch * 1024 + lane * 16;
      int r = olin >> 7;
      int cel = ((olin ^ ((r & 7) << 4)) >> 1) & 63;
      gload16(A + (size_t)(row0 + r) * K + k0 + cel, (char*)Als + ch * 1024);
    }
#pragma unroll
    for (int i = 0; i < 4; ++i) {
      int ch = i * 4 + wave;
      int olin = ch * 1024 + lane * 16;
      int r = olin >> 7;
      int cel = ((olin ^ ((r & 7) << 4)) >> 1) & 63;
      gload16(Bw + (size_t)(col0 + r) * K + k0 + cel, (char*)Bls + ch * 1024);
    }
    __syncthreads();
#pragma unroll
    for (int ks = 0; ks < 2; ++ks) {
      bf16x8 af[4], bfv[4];
      int cb = (ks * 32 + g * 8) * 2;
#pragma unroll
      for (int mi = 0; mi < 4; ++mi) {
        int r = wm + mi * 16 + ln15;
        af[mi] = *(const bf16x8*)((const char*)Als + r * 128 + (cb ^ ((r & 7) << 4)));
      }
#pragma unroll
      for (int ni = 0; ni < 4; ++ni) {
        int r = wn + ni * 16 + ln15;
        bfv[ni] = *(const bf16x8*)((const char*)Bls + r * 128 + (cb ^ ((r & 7) << 4)));
      }
#pragma unroll
      for (int mi = 0; mi < 4; ++mi)
#pragma unroll
        for (int ni = 0; ni < 4; ++ni)
          acc[mi][ni] = MFMA16(af[mi], bfv[ni], acc[mi][ni]);
    }
    __syncthreads();
  }

#pragma unroll
  for (int mi = 0; mi < 4; ++mi)
#pragma unroll
    for (int ni = 0; ni < 4; ++ni)
#pragma unroll
      for (int r = 0; r < 4; ++r) {
        int row = row0 + wm + mi * 16 + g * 4 + r;
        int col = col0 + wn + ni * 16 + ln15;
        outf[(size_t)row * N + col] = acc[mi][ni][r] + bias[col];
      }
}

// ---------------- fused windowed attention (v7: half-bucket blocks) ---------------
// block = (b, h, bucket, half): 4 waves x 32 q-rows = 128 rows; grid 1024.
// Single-buffered Kc + conditional stages (block-uniform need test skips stage AND
// its barriers). Lazy prev-view Q. LDS ~34.5KB -> 4 blocks/CU.
__global__ __launch_bounds__(256, 4) void attn_kernel(
    const u16* __restrict__ qrot,   // (B,H,L,64) rotated by R(l%256), scaled 0.125
    const u16* __restrict__ krot,   // (B,H,L,64) rotated by R(256+l%256)
    const u16* __restrict__ vT,     // (B,H,64,L)
    const int* __restrict__ cell,   // (B,L)
    const float* __restrict__ ropc, const float* __restrict__ rops,
    u16* __restrict__ o) {          // (B,L,1024) bf16
  __shared__ __align__(16) u16 Kc[128 * 64];   // one K stage (128 cols x 64 d), 16KB
  __shared__ __align__(16) u16 Pl[4 * 32 * 64];// per-wave P relay, swizzled, 16KB
  __shared__ int ci[128];
  __shared__ int cj[512];

  const int tid = threadIdx.x, lane = tid & 63, wave = tid >> 6;
  const int g = lane >> 4, ln15 = lane & 15;
  // XCD-contiguous mapping: consecutive lin within an XCD share K/V windows
  const int lin = (blockIdx.x & 7) * 128 + (blockIdx.x >> 3);
  const int half = lin & 1;
  const int bucket = (lin >> 1) & 15;
  const int h = (lin >> 5) & 15;
  const int b = lin >> 9;
  const int w0 = bucket * 256;
  const int r0 = half * 128;  // block row base within bucket
  const size_t base = (size_t)(b * HEADS + h) * LSEQ * HD;

  if (tid < 128) ci[tid] = cell[b * LSEQ + w0 + r0 + tid];
  {
    int j = tid;
#pragma unroll
    for (int it = 0; it < 2; ++it, j += 256) {
      int gj = w0 - 256 + j;
      cj[j] = (gj >= 0) ? cell[b * LSEQ + gj] : (int)0x80000000;
    }
  }
  __syncthreads();  // ci/cj visible to all waves

  // Q fragments (already rotated + scaled)
  bf16x8 qf[2][2];
#pragma unroll
  for (int mi = 0; mi < 2; ++mi)
#pragma unroll
    for (int ks = 0; ks < 2; ++ks)
      qf[mi][ks] = *(const bf16x8*)(qrot + base +
          (size_t)(w0 + r0 + wave * 32 + mi * 16 + ln15) * HD + ks * 32 + g * 8);

  const int crb_lo = ci[0], crb_hi = ci[127];
  const int crw_lo = ci[wave * 32], crw_hi = ci[wave * 32 + 31];

#define CHUNK_NEED(kk) (!(cj[(kk) * 64 + 63] < crb_lo || cj[(kk) * 64] > crb_hi))

  // prev-view Q: q~ = R(256) * qf, built only if any prev-half chunk is needed
  bf16x8 qfB[2][2] = {qf[0][0], qf[0][1], qf[1][0], qf[1][1]};
  const bool needB = (bucket > 0) &&
      (CHUNK_NEED(0) || CHUNK_NEED(1) || CHUNK_NEED(2) || CHUNK_NEED(3));
  if (needB) {
#pragma unroll
    for (int ks = 0; ks < 2; ++ks) {
      const int d0 = ks * 32 + g * 8;
      float rc[8], rs8[8];
#pragma unroll
      for (int j = 0; j < 8; ++j) {
        rc[j] = ropc[256 * 64 + d0 + j];
        rs8[j] = rops[256 * 64 + d0 + j];
      }
#pragma unroll
      for (int mi = 0; mi < 2; ++mi) {
        bf16x8 s = qf[mi][ks], t;
#pragma unroll
        for (int j = 0; j < 8; j += 2) {
          float e = b2f((u16)s[j]), od = b2f((u16)s[j + 1]);
          t[j]     = (short)f2b(e * rc[j] - od * rs8[j]);
          t[j + 1] = (short)f2b(e * rs8[j] + od * rc[j]);
        }
        qfB[mi][ks] = t;
      }
    }
  }

  f32x4 Oa[2][4] = {};
  float mrow[2][4], lrow[2][4];
#pragma unroll
  for (int a1 = 0; a1 < 2; ++a1)
#pragma unroll
    for (int a2 = 0; a2 < 4; ++a2) { mrow[a1][a2] = NEGF; lrow[a1][a2] = 0.f; }

  const int s0 = (bucket == 0) ? 2 : 0;
  for (int s = s0; s < 4; ++s) {
    // block-uniform stage need: block-causal + cell-interval intersect
    if (s * 128 > r0 + 383) continue;                       // half=0 never needs stage 3
    if (!(CHUNK_NEED(s * 2) || CHUNK_NEED(s * 2 + 1))) continue;

    __syncthreads();  // prior stage's Kc readers done (uniform branch)
    {                 // stage 128 K-cols (16KB) via global_load_lds, swizzled source
      int gj0_ = w0 - 256 + s * 128;
#pragma unroll
      for (int i_ = 0; i_ < 4; ++i_) {
        int ch_ = i_ * 4 + wave;
        int olin_ = ch_ * 1024 + lane * 16;
        int r_ = olin_ >> 7;
        int cel_ = ((olin_ ^ ((r_ & 7) << 4)) >> 1) & 63;
        gload16(krot + base + (size_t)(gj0_ + r_) * HD + cel_, (char*)Kc + ch_ * 1024);
      }
    }
    __syncthreads();  // Kc ready

#pragma unroll
    for (int sub = 0; sub < 2; ++sub) {
      const int k = s * 2 + sub;                       // 64-col chunk index 0..7
      if (k * 64 > r0 + wave * 32 + 287) continue;     // per-wave causal
      {                                                // per-wave cell-interval skip
        int clo = cj[k * 64], chi = cj[k * 64 + 63];
        if (chi < crw_lo || clo > crw_hi) continue;
      }
      const int gj0 = w0 - 256 + k * 64;
      const int lr0 = sub * 64;
      const bool prevhalf = (k < 4);

#pragma unroll
      for (int mi = 0; mi < 2; ++mi) {
        f32x4 sc[4] = {};
        __builtin_amdgcn_s_setprio(1);
#pragma unroll
        for (int ks = 0; ks < 2; ++ks) {
          int cb = (ks * 32 + g * 8) * 2;
          bf16x8 aq = prevhalf ? qfB[mi][ks] : qf[mi][ks];
#pragma unroll
          for (int ni = 0; ni < 4; ++ni) {
            int r = lr0 + ni * 16 + ln15;
            bf16x8 kf = *(const bf16x8*)((const char*)Kc + r * 128 + (cb ^ ((r & 7) << 4)));
            sc[ni] = MFMA16(aq, kf, sc[ni]);
          }
        }
        __builtin_amdgcn_s_setprio(0);
        // mask + row max (scores pre-scaled via Q)
        float mx[4] = {NEGF, NEGF, NEGF, NEGF};
#pragma unroll
        for (int ni = 0; ni < 4; ++ni)
#pragma unroll
          for (int r = 0; r < 4; ++r) {
            int rblk = wave * 32 + mi * 16 + g * 4 + r;   // block-local row
            int iloc = r0 + rblk;                          // bucket-local row
            int p = k * 64 + ni * 16 + ln15;
            bool ok = (p <= iloc + 256) && (ci[rblk] == cj[p]);
            float sv = ok ? sc[ni][r] : NEGF;
            sc[ni][r] = sv;
            mx[r] = fmaxf(mx[r], sv);
          }
#pragma unroll
        for (int d = 1; d < 16; d <<= 1)
#pragma unroll
          for (int r = 0; r < 4; ++r) mx[r] = fmaxf(mx[r], __shfl_xor(mx[r], d));
        float rs[4] = {0.f, 0.f, 0.f, 0.f};
        // T13 defer-max: rescale only if max grew by > 8
        bool big = false;
#pragma unroll
        for (int r = 0; r < 4; ++r) big = big || (mx[r] > mrow[mi][r] + 8.0f);
        if (__any(big)) {
#pragma unroll
          for (int r = 0; r < 4; ++r) {
            float mold = mrow[mi][r];
            float mnew = fmaxf(mold, mx[r]);
            float alpha = __expf(mold - mnew);  // NEG,NEG -> 1; NEG,finite -> 0
            mrow[mi][r] = mnew;
            lrow[mi][r] *= alpha;
#pragma unroll
            for (int nd = 0; nd < 4; ++nd) Oa[mi][nd][r] *= alpha;
          }
        }
#pragma unroll
        for (int ni = 0; ni < 4; ++ni)
#pragma unroll
          for (int r = 0; r < 4; ++r) {
            float sv = sc[ni][r];
            float p = (sv > NEGF * 0.5f) ? __expf(sv - mrow[mi][r]) : 0.f;
            rs[r] += p;
            int row = mi * 16 + g * 4 + r;
            int colb = (ni * 16 + ln15) * 2;
            *(u16*)((char*)Pl + wave * 4096 + row * 128 + (colb ^ ((row & 7) << 4))) = f2b(p);
          }
#pragma unroll
        for (int d = 1; d < 16; d <<= 1)
#pragma unroll
          for (int r = 0; r < 4; ++r) rs[r] += __shfl_xor(rs[r], d);
#pragma unroll
        for (int r = 0; r < 4; ++r) lrow[mi][r] += rs[r];
      }  // mi

      // PV: O += P(32x64) * V(64x64); V fragments direct from global
#pragma unroll
      for (int jb = 0; jb < 2; ++jb) {
        bf16x8 pa[2], vb[4];
        int cb = (jb * 32 + g * 8) * 2;
#pragma unroll
        for (int mi = 0; mi < 2; ++mi) {
          int row = mi * 16 + ln15;
          pa[mi] = *(const bf16x8*)((const char*)Pl + wave * 4096 + row * 128 + (cb ^ ((row & 7) << 4)));
        }
#pragma unroll
        for (int nd = 0; nd < 4; ++nd) {
          int d = nd * 16 + ln15;
          int p0 = gj0 + jb * 32 + g * 8;
          vb[nd] = *(const bf16x8*)(vT + base + (size_t)d * LSEQ + p0);
        }
        __builtin_amdgcn_s_setprio(1);
#pragma unroll
        for (int mi = 0; mi < 2; ++mi)
#pragma unroll
          for (int nd = 0; nd < 4; ++nd) Oa[mi][nd] = MFMA16(pa[mi], vb[nd], Oa[mi][nd]);
        __builtin_amdgcn_s_setprio(0);
      }
    }  // sub
  }  // stages

  // epilogue: normalize and store
#pragma unroll
  for (int mi = 0; mi < 2; ++mi)
#pragma unroll
    for (int r = 0; r < 4; ++r) {
      float invl = 1.0f / lrow[mi][r];
      int gi = w0 + r0 + wave * 32 + mi * 16 + g * 4 + r;
      size_t ob = ((size_t)b * LSEQ + gi) * DM + h * HD;
#pragma unroll
      for (int nd = 0; nd < 4; ++nd) o[ob + nd * 16 + ln15] = f2b(Oa[mi][nd][r] * invl);
    }
#undef CHUNK_NEED
}

extern "C" void kernel_launch(void* const* d_in, const int* in_sizes, int n_in,
                              void* d_out, int out_size, void* d_ws, size_t ws_size,
                              hipStream_t stream) {
  const float* q = (const float*)d_in[0];
  const float* k = (const float*)d_in[1];
  const float* v = (const float*)d_in[2];
  const int* cell = (const int*)d_in[3];
  const float* lnw[4] = {(const float*)d_in[4], (const float*)d_in[8], (const float*)d_in[12], (const float*)d_in[16]};
  const float* lnb[4] = {(const float*)d_in[5], (const float*)d_in[9], (const float*)d_in[13], (const float*)d_in[17]};
  const float* Wm[4]  = {(const float*)d_in[6], (const float*)d_in[10], (const float*)d_in[14], (const float*)d_in[18]};
  const float* bi[4]  = {(const float*)d_in[7], (const float*)d_in[11], (const float*)d_in[15], (const float*)d_in[19]};

  char* ws = (char*)d_ws;
  u16* xlnq  = (u16*)(ws);               // 16 MiB: LN'd q (also reused for LN(o))
  u16* wbf   = (u16*)(ws + 16777216);    // 8 MiB: 4 bf16 weights
  u16* qrot  = (u16*)(ws + 25165824);    // 16 MiB
  u16* krot  = (u16*)(ws + 41943040);    // 16 MiB (single K view)
  u16* vT    = (u16*)(ws + 75497472);    // 16 MiB
  u16* obuf  = (u16*)(ws + 92274688);    // 16 MiB: xln_k, then attn output
  float* ropc = (float*)(ws + 109051904);
  float* rops = (float*)(ws + 109182976);  // end ~104.3 MiB
  u16* xlnk = obuf;                      // alias: free until attn writes
  u16* xlnv = (u16*)d_out;               // scratch in d_out (fully overwritten by gemm_o)

  cvtw<<<1024, 256, 0, stream>>>((const float4*)Wm[0], (const float4*)Wm[1],
                                 (const float4*)Wm[2], (const float4*)Wm[3], (ushort4*)wbf);
  rope_build<<<512, 64, 0, stream>>>(ropc, rops);

  dim3 lng(8192, 3);
  ln_qkv<<<lng, 256, 0, stream>>>((const float4*)q, (const float4*)k, (const float4*)v,
                                  lnw[0], lnb[0], lnw[1], lnb[1], lnw[2], lnb[2],
                                  (ushort4*)xlnq, (ushort4*)xlnk, (ushort4*)xlnv);
  dim3 gq(512, 3);
  gemm_qkv<<<gq, 256, 0, stream>>>(xlnq, xlnk, xlnv, wbf, bi[0], bi[1], bi[2],
                                   ropc, rops, qrot, krot, vT);
  attn_kernel<<<1024, 256, 0, stream>>>(qrot, krot, vT, cell, ropc, rops, obuf);
  ln_rows<<<8192, 256, 0, stream>>>((const ushort4*)obuf, lnw[3], lnb[3], (ushort4*)xlnq);
  gemm_o<<<512, 256, 0, stream>>>(xlnq, wbf + 3145728, bi[3], (float*)d_out);
}

// Round 11
// 193.952 us; speedup vs baseline: 1.1915x; 1.1915x over previous
//
#include <hip/hip_runtime.h>

#define HEADS 16
#define HD 64
#define DM 1024
#define LSEQ 4096
#define NEGF (-1.0e30f)

typedef __attribute__((ext_vector_type(8))) short bf16x8;
typedef __attribute__((ext_vector_type(4))) float f32x4;
typedef unsigned short u16;

#define MFMA16(a, b, c) __builtin_amdgcn_mfma_f32_16x16x32_bf16((a), (b), (c), 0, 0, 0)

static __device__ __forceinline__ float b2f(u16 u) {
  union { float f; unsigned i; } t; t.i = ((unsigned)u) << 16; return t.f;
}
static __device__ __forceinline__ u16 f2b(float f) {
  union { float f; unsigned i; } t; t.f = f;
  unsigned r = t.i + 0x7fffu + ((t.i >> 16) & 1u);
  return (u16)(r >> 16);
}
static __device__ __forceinline__ ushort4 pk4(float4 v) {
  return make_ushort4(f2b(v.x), f2b(v.y), f2b(v.z), f2b(v.w));
}
static __device__ __forceinline__ void gload16(const void* g, void* l) {
  __builtin_amdgcn_global_load_lds((const __attribute__((address_space(1))) void*)g,
                                   (__attribute__((address_space(3))) void*)l, 16, 0, 0);
}

// ---------------- fused preamble: ln_qkv (24576 blocks) + cvtw (1024) + rope (128) -
// All three are mutually independent producers for gemm_qkv; one dispatch removes
// two launch/drain boundaries. Branches are block-uniform.
__global__ __launch_bounds__(256) void prep(
    const float4* __restrict__ q, const float4* __restrict__ k, const float4* __restrict__ v,
    const float* __restrict__ g0, const float* __restrict__ b0,
    const float* __restrict__ g1, const float* __restrict__ b1,
    const float* __restrict__ g2, const float* __restrict__ b2,
    ushort4* __restrict__ o0, ushort4* __restrict__ o1, ushort4* __restrict__ o2,
    const float4* __restrict__ w0, const float4* __restrict__ w1,
    const float4* __restrict__ w2, const float4* __restrict__ w3,
    ushort4* __restrict__ wout,
    float* __restrict__ ropc, float* __restrict__ rops) {
  const int bid = blockIdx.x, tid = threadIdx.x;
  if (bid < 24576) {  // ---- ln_qkv: row = bid & 8191, sel = bid >> 13
    const int row = bid & 8191, sel = bid >> 13;
    const float4* src = (sel == 0) ? q : (sel == 1) ? k : v;
    const float* gam = (sel == 0) ? g0 : (sel == 1) ? g1 : g2;
    const float* bet = (sel == 0) ? b0 : (sel == 1) ? b1 : b2;
    ushort4* dst = (sel == 0) ? o0 : (sel == 1) ? o1 : o2;

    float4 v4 = src[(size_t)row * 256 + tid];
    float s = v4.x + v4.y + v4.z + v4.w;
    float s2 = v4.x * v4.x + v4.y * v4.y + v4.z * v4.z + v4.w * v4.w;
#pragma unroll
    for (int d = 1; d < 64; d <<= 1) { s += __shfl_xor(s, d); s2 += __shfl_xor(s2, d); }
    __shared__ float ps[8];
    int lane = tid & 63, wave = tid >> 6;
    if (lane == 0) { ps[wave] = s; ps[4 + wave] = s2; }
    __syncthreads();
    float tot = ps[0] + ps[1] + ps[2] + ps[3];
    float tot2 = ps[4] + ps[5] + ps[6] + ps[7];
    float mean = tot * (1.f / 1024.f);
    float var = tot2 * (1.f / 1024.f) - mean * mean;
    float rstd = rsqrtf(var + 1e-5f);
    float4 gv = ((const float4*)gam)[tid];
    float4 bv = ((const float4*)bet)[tid];
    dst[(size_t)row * 256 + tid] = make_ushort4(
        f2b((v4.x - mean) * rstd * gv.x + bv.x), f2b((v4.y - mean) * rstd * gv.y + bv.y),
        f2b((v4.z - mean) * rstd * gv.z + bv.z), f2b((v4.w - mean) * rstd * gv.w + bv.w));
  } else if (bid < 25600) {  // ---- cvtw: weights f32 -> bf16
    int i = (bid - 24576) * 256 + tid;  // 0..262143 float4 units
    wout[i]          = pk4(w0[i]);
    wout[i + 262144] = pk4(w1[i]);
    wout[i + 524288] = pk4(w2[i]);
    wout[i + 786432] = pk4(w3[i]);
  } else {  // ---- rope tables: 512 positions x 64 dims
    int idx = (bid - 25600) * 256 + tid;  // 0..32767
    int p = idx >> 6, d = idx & 63;
    int t2 = d & ~1;
    double inv = pow(10000.0, -(double)t2 / 64.0);
    double f = (double)p * inv;
    ropc[idx] = (float)cos(f);
    rops[idx] = (float)sin(f);
  }
}

// ---------------- LayerNorm rows (bf16 in, bf16 out) — for O projection -----------
__global__ __launch_bounds__(256) void ln_rows(const ushort4* __restrict__ xin,
                                               const float* __restrict__ gam,
                                               const float* __restrict__ bet,
                                               ushort4* __restrict__ out) {
  int row = blockIdx.x, tid = threadIdx.x;
  ushort4 u = xin[(size_t)row * 256 + tid];
  float4 v;
  v.x = b2f(u.x); v.y = b2f(u.y); v.z = b2f(u.z); v.w = b2f(u.w);
  float s = v.x + v.y + v.z + v.w;
  float s2 = v.x * v.x + v.y * v.y + v.z * v.z + v.w * v.w;
#pragma unroll
  for (int d = 1; d < 64; d <<= 1) { s += __shfl_xor(s, d); s2 += __shfl_xor(s2, d); }
  __shared__ float ps[8];
  int lane = tid & 63, wave = tid >> 6;
  if (lane == 0) { ps[wave] = s; ps[4 + wave] = s2; }
  __syncthreads();
  float tot = ps[0] + ps[1] + ps[2] + ps[3];
  float tot2 = ps[4] + ps[5] + ps[6] + ps[7];
  float mean = tot * (1.f / 1024.f);
  float var = tot2 * (1.f / 1024.f) - mean * mean;
  float rstd = rsqrtf(var + 1e-5f);
  float4 gv = ((const float4*)gam)[tid];
  float4 bv = ((const float4*)bet)[tid];
  out[(size_t)row * 256 + tid] = make_ushort4(
      f2b((v.x - mean) * rstd * gv.x + bv.x), f2b((v.y - mean) * rstd * gv.y + bv.y),
      f2b((v.z - mean) * rstd * gv.z + bv.z), f2b((v.w - mean) * rstd * gv.w + bv.w));
}

// ---------------- fused QKV NT GEMM (blockIdx.y = mode 0/1/2) ---------------------
// mode 0 = Q (scaled 0.125, rotary pos=l%256 -> qrot BHLd)
// mode 1 = K (rotary pos=256+l%256 -> krot BHLd; single view — prev view derived in attn)
// mode 2 = V (bf16 transposed BHdL -> vT)
// Epilogue stages C through LDS (overlaying Als/Bls) -> 16B coalesced stores.
__global__ __launch_bounds__(256, 3) void gemm_qkv(
    const u16* __restrict__ Aq, const u16* __restrict__ Ak, const u16* __restrict__ Av,
    const u16* __restrict__ wbf,
    const float* __restrict__ bq, const float* __restrict__ bk, const float* __restrict__ bv,
    const float* __restrict__ ropc, const float* __restrict__ rops,
    u16* __restrict__ qrot, u16* __restrict__ krot, u16* __restrict__ vTp) {
  __shared__ __align__(16) char smem[34816];  // staging 32KB; epilogue C-tile 128x136 u16
  u16* Als = (u16*)smem;
  u16* Bls = (u16*)(smem + 16384);
  const int tid = threadIdx.x, lane = tid & 63, wave = tid >> 6;
  const int g = lane >> 4, ln15 = lane & 15;
  const int mode = blockIdx.y;
  const u16* A = (mode == 0) ? Aq : (mode == 1) ? Ak : Av;
  const u16* Bw = wbf + (size_t)mode * 1048576;
  const float* bias = (mode == 0) ? bq : (mode == 1) ? bk : bv;
  // XCD-chunked swizzle on x (bijective; 512 blocks, 64 M-tiles x 8 N-tiles)
  const int bid = blockIdx.x;
  const int xcd = bid & 7, idx = bid >> 3;
  const int row0 = (xcd * 8 + (idx >> 3)) * 128;
  const int col0 = (idx & 7) * 128;
  const int wm = (wave >> 1) * 64, wn = (wave & 1) * 64;
  const int K = 1024;
  f32x4 acc[4][4] = {};

  for (int k0 = 0; k0 < K; k0 += 64) {
#pragma unroll
    for (int i = 0; i < 4; ++i) {  // A tile: 16KB, swizzled via pre-swizzled source
      int ch = i * 4 + wave;
      int olin = ch * 1024 + lane * 16;
      int r = olin >> 7;
      int cel = ((olin ^ ((r & 7) << 4)) >> 1) & 63;
      gload16(A + (size_t)(row0 + r) * K + k0 + cel, (char*)Als + ch * 1024);
    }
#pragma unroll
    for (int i = 0; i < 4; ++i) {  // B tile
      int ch = i * 4 + wave;
      int olin = ch * 1024 + lane * 16;
      int r = olin >> 7;
      int cel = ((olin ^ ((r & 7) << 4)) >> 1) & 63;
      gload16(Bw + (size_t)(col0 + r) * K + k0 + cel, (char*)Bls + ch * 1024);
    }
    __syncthreads();
#pragma unroll
    for (int ks = 0; ks < 2; ++ks) {
      bf16x8 af[4], bfv[4];
      int cb = (ks * 32 + g * 8) * 2;
#pragma unroll
      for (int mi = 0; mi < 4; ++mi) {
        int r = wm + mi * 16 + ln15;
        af[mi] = *(const bf16x8*)((const char*)Als + r * 128 + (cb ^ ((r & 7) << 4)));
      }
#pragma unroll
      for (int ni = 0; ni < 4; ++ni) {
        int r = wn + ni * 16 + ln15;
        bfv[ni] = *(const bf16x8*)((const char*)Bls + r * 128 + (cb ^ ((r & 7) << 4)));
      }
#pragma unroll
      for (int mi = 0; mi < 4; ++mi)
#pragma unroll
        for (int ni = 0; ni < 4; ++ni)
          acc[mi][ni] = MFMA16(af[mi], bfv[ni], acc[mi][ni]);
    }
    __syncthreads();
  }

  // ---- epilogue: rotary (f32, single rounding) + LDS-staged coalesced writes ----
  u16* Cl = (u16*)smem;  // 128 x 136 u16 (stride 272B: 16B-aligned rows, bank-spread)
#pragma unroll
  for (int mi = 0; mi < 4; ++mi)
#pragma unroll
    for (int ni = 0; ni < 4; ++ni)
#pragma unroll
      for (int r = 0; r < 4; ++r) {
        int rowc = wm + mi * 16 + g * 4 + r;
        int colc = wn + ni * 16 + ln15;
        int row = row0 + rowc, col = col0 + colc;
        float val = acc[mi][ni][r] + bias[col];
        if (mode == 2) {
          Cl[colc * 136 + rowc] = f2b(val);  // transposed store for (B,H,d,L) out
        } else {
          if (mode == 0) val *= 0.125f;      // fold 1/sqrt(hd) into Q
          float oth = __shfl_xor(val, 1);    // rotary partner (adjacent dim = adjacent lane)
          int d = col & 63;
          int pp = (row & 255) + ((mode == 1) ? 256 : 0);
          float cc = ropc[pp * 64 + d], ss = rops[pp * 64 + d];
          Cl[rowc * 136 + colc] = f2b((d & 1) ? (val * cc + oth * ss) : (val * cc - oth * ss));
        }
      }
  __syncthreads();
  if (mode == 2) {
#pragma unroll
    for (int i = 0; i < 8; ++i) {
      int c2 = i * 256 + tid;
      int dloc = c2 >> 4, lgrp = c2 & 15;
      bf16x8 vv = *(const bf16x8*)(Cl + dloc * 136 + lgrp * 8);
      int colg = col0 + dloc, hh = colg >> 6, d = colg & 63;
      int l = row0 + lgrp * 8, bb = l >> 12, ll = l & 4095;
      *(bf16x8*)(vTp + (((size_t)bb * HEADS + hh) * HD + d) * LSEQ + ll) = vv;
    }
  } else {
    u16* dst = (mode == 0) ? qrot : krot;
#pragma unroll
    for (int i = 0; i < 8; ++i) {
      int c2 = i * 256 + tid;
      int rowc = c2 >> 4, cgrp = c2 & 15;
      bf16x8 vv = *(const bf16x8*)(Cl + rowc * 136 + cgrp * 8);
      int l = row0 + rowc, bb = l >> 12, ll = l & 4095;
      int colg = col0 + cgrp * 8, hh = colg >> 6, d0 = colg & 63;
      *(bf16x8*)(dst + (((size_t)bb * HEADS + hh) * LSEQ + ll) * HD + d0) = vv;
    }
  }
}

// ---------------- final NT GEMM: out = LN(o) @ Wo^T + bias (f32) ------------------
__global__ __launch_bounds__(256, 3) void gemm_o(
    const u16* __restrict__ A, const u16* __restrict__ Bw, const float* __restrict__ bias,
    float* __restrict__ outf) {
  __shared__ __align__(16) u16 Als[128 * 64];
  __shared__ __align__(16) u16 Bls[128 * 64];
  const int tid = threadIdx.x, lane = tid & 63, wave = tid >> 6;
  const int g = lane >> 4, ln15 = lane & 15;
  const int bid = blockIdx.x;
  const int xcd = bid & 7, idx = bid >> 3;
  const int row0 = (xcd * 8 + (idx >> 3)) * 128;
  const int col0 = (idx & 7) * 128;
  const int wm = (wave >> 1) * 64, wn = (wave & 1) * 64;
  const int K = 1024, N = 1024;
  f32x4 acc[4][4] = {};

  for (int k0 = 0; k0 < K; k0 += 64) {
#pragma unroll
    for (int i = 0; i < 4; ++i) {
      int ch = i * 4 + wave;
      int olin = ch * 1024 + lane * 16;
      int r = olin >> 7;
      int cel = ((olin ^ ((r & 7) << 4)) >> 1) & 63;
      gload16(A + (size_t)(row0 + r) * K + k0 + cel, (char*)Als + ch * 1024);
    }
#pragma unroll
    for (int i = 0; i < 4; ++i) {
      int ch = i * 4 + wave;
      int olin = ch * 1024 + lane * 16;
      int r = olin >> 7;
      int cel = ((olin ^ ((r & 7) << 4)) >> 1) & 63;
      gload16(Bw + (size_t)(col0 + r) * K + k0 + cel, (char*)Bls + ch * 1024);
    }
    __syncthreads();
#pragma unroll
    for (int ks = 0; ks < 2; ++ks) {
      bf16x8 af[4], bfv[4];
      int cb = (ks * 32 + g * 8) * 2;
#pragma unroll
      for (int mi = 0; mi < 4; ++mi) {
        int r = wm + mi * 16 + ln15;
        af[mi] = *(const bf16x8*)((const char*)Als + r * 128 + (cb ^ ((r & 7) << 4)));
      }
#pragma unroll
      for (int ni = 0; ni < 4; ++ni) {
        int r = wn + ni * 16 + ln15;
        bfv[ni] = *(const bf16x8*)((const char*)Bls + r * 128 + (cb ^ ((r & 7) << 4)));
      }
#pragma unroll
      for (int mi = 0; mi < 4; ++mi)
#pragma unroll
        for (int ni = 0; ni < 4; ++ni)
          acc[mi][ni] = MFMA16(af[mi], bfv[ni], acc[mi][ni]);
    }
    __syncthreads();
  }

#pragma unroll
  for (int mi = 0; mi < 4; ++mi)
#pragma unroll
    for (int ni = 0; ni < 4; ++ni)
#pragma unroll
      for (int r = 0; r < 4; ++r) {
        int row = row0 + wm + mi * 16 + g * 4 + r;
        int col = col0 + wn + ni * 16 + ln15;
        outf[(size_t)row * N + col] = acc[mi][ni][r] + bias[col];
      }
}

// ---------------- fused windowed attention (v6: single-K, derived prev-view Q) ----
// block = (b, h, bucket); 8 waves x 32 q-rows; K staged 128 cols/stage, dbuf.
// krot holds R(256+p)k; for prev-bucket chunks use q~ = R(256)*qrot (rotation
// composition: <R(i)q, R(p)k> == <R(256+i)q, R(256+p)k>). cell sorted -> interval skip.
__global__ __launch_bounds__(512, 2) void attn_kernel(
    const u16* __restrict__ qrot,   // (B,H,L,64) rotated by R(l%256), scaled 0.125
    const u16* __restrict__ krot,   // (B,H,L,64) rotated by R(256+l%256)
    const u16* __restrict__ vT,     // (B,H,64,L)
    const int* __restrict__ cell,   // (B,L)
    const float* __restrict__ ropc, const float* __restrict__ rops,
    u16* __restrict__ o) {          // (B,L,1024) bf16
  __shared__ __align__(16) u16 Kc[2][128 * 64];  // dbuf K stages, swizzled, 2x16KB
  __shared__ __align__(16) u16 Pl[8 * 32 * 64];  // per-wave P relay, swizzled, 32KB
  __shared__ int ci[256];
  __shared__ int cj[512];

  const int tid = threadIdx.x, lane = tid & 63, wave = tid >> 6;
  const int g = lane >> 4, ln15 = lane & 15;
  const int bucket = blockIdx.x & 15;
  const int h = (blockIdx.x >> 4) & 15;
  const int b = blockIdx.x >> 8;
  const int w0 = bucket * 256;
  const size_t base = (size_t)(b * HEADS + h) * LSEQ * HD;

  if (tid < 256) ci[tid] = cell[b * LSEQ + w0 + tid];
  {
    int gj = w0 - 256 + tid;
    cj[tid] = (gj >= 0) ? cell[b * LSEQ + gj] : (int)0x80000000;
  }

  // Q fragments (already rotated + scaled): rows w0 + wave*32 + mi*16 + ln15
  bf16x8 qf[2][2];
#pragma unroll
  for (int mi = 0; mi < 2; ++mi)
#pragma unroll
    for (int ks = 0; ks < 2; ++ks)
      qf[mi][ks] = *(const bf16x8*)(qrot + base +
          (size_t)(w0 + wave * 32 + mi * 16 + ln15) * HD + ks * 32 + g * 8);

  // prev-view Q: q~ = R(256) * qf (fixed-angle in-register rotation, once per block)
  bf16x8 qfB[2][2];
#pragma unroll
  for (int ks = 0; ks < 2; ++ks) {
    const int d0 = ks * 32 + g * 8;
    float rc[8], rs8[8];
#pragma unroll
    for (int j = 0; j < 8; ++j) {
      rc[j] = ropc[256 * 64 + d0 + j];
      rs8[j] = rops[256 * 64 + d0 + j];
    }
#pragma unroll
    for (int mi = 0; mi < 2; ++mi) {
      bf16x8 s = qf[mi][ks], t;
#pragma unroll
      for (int j = 0; j < 8; j += 2) {
        float e = b2f((u16)s[j]), od = b2f((u16)s[j + 1]);
        t[j]     = (short)f2b(e * rc[j] - od * rs8[j]);
        t[j + 1] = (short)f2b(e * rs8[j] + od * rc[j]);
      }
      qfB[mi][ks] = t;
    }
  }

  f32x4 Oa[2][4] = {};
  float mrow[2][4], lrow[2][4];
#pragma unroll
  for (int a1 = 0; a1 < 2; ++a1)
#pragma unroll
    for (int a2 = 0; a2 < 4; ++a2) { mrow[a1][a2] = NEGF; lrow[a1][a2] = 0.f; }

#define STAGE_K(bi, s)                                                          \
  {                                                                             \
    int gj0_ = w0 - 256 + (s) * 128;                                            \
    _Pragma("unroll")                                                           \
    for (int i_ = 0; i_ < 2; ++i_) {                                            \
      int ch_ = i_ * 8 + wave;                                                  \
      int olin_ = ch_ * 1024 + lane * 16;                                       \
      int r_ = olin_ >> 7;                                                      \
      int cel_ = ((olin_ ^ ((r_ & 7) << 4)) >> 1) & 63;                         \
      gload16(krot + base + (size_t)(gj0_ + r_) * HD + cel_,                    \
              (char*)Kc[bi] + ch_ * 1024);                                      \
    }                                                                           \
  }

  const int s0 = (bucket == 0) ? 2 : 0;
  STAGE_K(0, s0);
  __syncthreads();  // stage s0 ready; ci/cj visible

  // cell intervals (sorted): block rows, this wave's rows
  const int crb_lo = ci[0], crb_hi = ci[255];
  const int crw_lo = ci[wave * 32], crw_hi = ci[wave * 32 + 31];

  for (int s = s0; s < 4; ++s) {
    const int cur = (s - s0) & 1;
    if (s + 1 < 4) {
      // block-level staging skip: stage needed iff any of its 2 chunks' cell range
      // intersects the block's row range (block skip => every wave skips it)
      int k1 = (s + 1) * 2;
      bool need = false;
#pragma unroll
      for (int kk = 0; kk < 2; ++kk) {
        int clo = cj[(k1 + kk) * 64], chi = cj[(k1 + kk) * 64 + 63];
        need = need || !(chi < crb_lo || clo > crb_hi);
      }
      if (need) STAGE_K(cur ^ 1, s + 1);
    }

    // two 64-col sub-chunks within this stage
#pragma unroll
    for (int sub = 0; sub < 2; ++sub) {
      const int k = s * 2 + sub;                   // 64-col chunk index 0..7
      if (k * 64 > wave * 32 + 287) continue;      // causal: no col in chunk reachable
      {                                            // cell-interval skip (exact)
        int clo = cj[k * 64], chi = cj[k * 64 + 63];
        if (chi < crw_lo || clo > crw_hi) continue;
      }
      const int gj0 = w0 - 256 + k * 64;           // global col base of chunk
      const int lr0 = sub * 64;                    // local row base in Kc stage
      const bool prevhalf = (k < 4);

#pragma unroll
      for (int mi = 0; mi < 2; ++mi) {
        f32x4 sc[4] = {};
        __builtin_amdgcn_s_setprio(1);
#pragma unroll
        for (int ks = 0; ks < 2; ++ks) {
          int cb = (ks * 32 + g * 8) * 2;
          bf16x8 aq = prevhalf ? qfB[mi][ks] : qf[mi][ks];
#pragma unroll
          for (int ni = 0; ni < 4; ++ni) {
            int r = lr0 + ni * 16 + ln15;
            bf16x8 kf = *(const bf16x8*)((const char*)Kc[cur] + r * 128 + (cb ^ ((r & 7) << 4)));
            sc[ni] = MFMA16(aq, kf, sc[ni]);
          }
        }
        __builtin_amdgcn_s_setprio(0);
        // mask + row max (scores pre-scaled via Q)
        float mx[4] = {NEGF, NEGF, NEGF, NEGF};
#pragma unroll
        for (int ni = 0; ni < 4; ++ni)
#pragma unroll
          for (int r = 0; r < 4; ++r) {
            int iloc = wave * 32 + mi * 16 + g * 4 + r;
            int p = k * 64 + ni * 16 + ln15;
            bool ok = (p <= iloc + 256) && (ci[iloc] == cj[p]);
            float sv = ok ? sc[ni][r] : NEGF;
            sc[ni][r] = sv;
            mx[r] = fmaxf(mx[r], sv);
          }
#pragma unroll
        for (int d = 1; d < 16; d <<= 1)
#pragma unroll
          for (int r = 0; r < 4; ++r) mx[r] = fmaxf(mx[r], __shfl_xor(mx[r], d));
        float rs[4] = {0.f, 0.f, 0.f, 0.f};
        // T13 defer-max: rescale only if max grew by > 8
        bool big = false;
#pragma unroll
        for (int r = 0; r < 4; ++r) big = big || (mx[r] > mrow[mi][r] + 8.0f);
        if (__any(big)) {
#pragma unroll
          for (int r = 0; r < 4; ++r) {
            float mold = mrow[mi][r];
            float mnew = fmaxf(mold, mx[r]);
            float alpha = __expf(mold - mnew);  // NEG,NEG -> 1; NEG,finite -> 0
            mrow[mi][r] = mnew;
            lrow[mi][r] *= alpha;
#pragma unroll
            for (int nd = 0; nd < 4; ++nd) Oa[mi][nd][r] *= alpha;
          }
        }
#pragma unroll
        for (int ni = 0; ni < 4; ++ni)
#pragma unroll
          for (int r = 0; r < 4; ++r) {
            float sv = sc[ni][r];
            float p = (sv > NEGF * 0.5f) ? __expf(sv - mrow[mi][r]) : 0.f;
            rs[r] += p;
            int row = mi * 16 + g * 4 + r;
            int colb = (ni * 16 + ln15) * 2;
            *(u16*)((char*)Pl + wave * 4096 + row * 128 + (colb ^ ((row & 7) << 4))) = f2b(p);
          }
#pragma unroll
        for (int d = 1; d < 16; d <<= 1)
#pragma unroll
          for (int r = 0; r < 4; ++r) rs[r] += __shfl_xor(rs[r], d);
#pragma unroll
        for (int r = 0; r < 4; ++r) lrow[mi][r] += rs[r];
      }  // mi

      // PV: O += P(32x64) * V(64x64); V fragments direct from global
#pragma unroll
      for (int jb = 0; jb < 2; ++jb) {
        bf16x8 pa[2], vb[4];
        int cb = (jb * 32 + g * 8) * 2;
#pragma unroll
        for (int mi = 0; mi < 2; ++mi) {
          int row = mi * 16 + ln15;
          pa[mi] = *(const bf16x8*)((const char*)Pl + wave * 4096 + row * 128 + (cb ^ ((row & 7) << 4)));
        }
#pragma unroll
        for (int nd = 0; nd < 4; ++nd) {
          int d = nd * 16 + ln15;
          int p0 = gj0 + jb * 32 + g * 8;
          vb[nd] = *(const bf16x8*)(vT + base + (size_t)d * LSEQ + p0);
        }
        __builtin_amdgcn_s_setprio(1);
#pragma unroll
        for (int mi = 0; mi < 2; ++mi)
#pragma unroll
          for (int nd = 0; nd < 4; ++nd) Oa[mi][nd] = MFMA16(pa[mi], vb[nd], Oa[mi][nd]);
        __builtin_amdgcn_s_setprio(0);
      }
    }  // sub

    __syncthreads();  // stage s+1 writes complete + all readers of Kc[cur] done
  }  // stages

  // epilogue: normalize and store
#pragma unroll
  for (int mi = 0; mi < 2; ++mi)
#pragma unroll
    for (int r = 0; r < 4; ++r) {
      float invl = 1.0f / lrow[mi][r];
      int gi = w0 + wave * 32 + mi * 16 + g * 4 + r;
      size_t ob = ((size_t)b * LSEQ + gi) * DM + h * HD;
#pragma unroll
      for (int nd = 0; nd < 4; ++nd) o[ob + nd * 16 + ln15] = f2b(Oa[mi][nd][r] * invl);
    }
#undef STAGE_K
}

extern "C" void kernel_launch(void* const* d_in, const int* in_sizes, int n_in,
                              void* d_out, int out_size, void* d_ws, size_t ws_size,
                              hipStream_t stream) {
  const float* q = (const float*)d_in[0];
  const float* k = (const float*)d_in[1];
  const float* v = (const float*)d_in[2];
  const int* cell = (const int*)d_in[3];
  const float* lnw[4] = {(const float*)d_in[4], (const float*)d_in[8], (const float*)d_in[12], (const float*)d_in[16]};
  const float* lnb[4] = {(const float*)d_in[5], (const float*)d_in[9], (const float*)d_in[13], (const float*)d_in[17]};
  const float* Wm[4]  = {(const float*)d_in[6], (const float*)d_in[10], (const float*)d_in[14], (const float*)d_in[18]};
  const float* bi[4]  = {(const float*)d_in[7], (const float*)d_in[11], (const float*)d_in[15], (const float*)d_in[19]};

  char* ws = (char*)d_ws;
  u16* xlnq  = (u16*)(ws);               // 16 MiB: LN'd q (also reused for LN(o))
  u16* wbf   = (u16*)(ws + 16777216);    // 8 MiB: 4 bf16 weights
  u16* qrot  = (u16*)(ws + 25165824);    // 16 MiB
  u16* krot  = (u16*)(ws + 41943040);    // 16 MiB (single K view)
  u16* vT    = (u16*)(ws + 75497472);    // 16 MiB
  u16* obuf  = (u16*)(ws + 92274688);    // 16 MiB: xln_k, then attn output
  float* ropc = (float*)(ws + 109051904);
  float* rops = (float*)(ws + 109182976);  // end ~104.3 MiB
  u16* xlnk = obuf;                      // alias: free until attn writes
  u16* xlnv = (u16*)d_out;               // scratch in d_out (fully overwritten by gemm_o)

  prep<<<25728, 256, 0, stream>>>(
      (const float4*)q, (const float4*)k, (const float4*)v,
      lnw[0], lnb[0], lnw[1], lnb[1], lnw[2], lnb[2],
      (ushort4*)xlnq, (ushort4*)xlnk, (ushort4*)xlnv,
      (const float4*)Wm[0], (const float4*)Wm[1], (const float4*)Wm[2], (const float4*)Wm[3],
      (ushort4*)wbf, ropc, rops);

  dim3 gq(512, 3);
  gemm_qkv<<<gq, 256, 0, stream>>>(xlnq, xlnk, xlnv, wbf, bi[0], bi[1], bi[2],
                                   ropc, rops, qrot, krot, vT);
  attn_kernel<<<512, 512, 0, stream>>>(qrot, krot, vT, cell, ropc, rops, obuf);
  ln_rows<<<8192, 256, 0, stream>>>((const ushort4*)obuf, lnw[3], lnb[3], (ushort4*)xlnq);
  gemm_o<<<512, 256, 0, stream>>>(xlnq, wbf + 3145728, bi[3], (float*)d_out);
}

// Round 12
// 191.201 us; speedup vs baseline: 1.2086x; 1.0144x over previous
//
#include <hip/hip_runtime.h>

#define HEADS 16
#define HD 64
#define DM 1024
#define LSEQ 4096
#define NEGF (-1.0e30f)

typedef __attribute__((ext_vector_type(8))) short bf16x8;
typedef __attribute__((ext_vector_type(4))) float f32x4;
typedef unsigned short u16;

#define MFMA16(a, b, c) __builtin_amdgcn_mfma_f32_16x16x32_bf16((a), (b), (c), 0, 0, 0)

static __device__ __forceinline__ float b2f(u16 u) {
  union { float f; unsigned i; } t; t.i = ((unsigned)u) << 16; return t.f;
}
static __device__ __forceinline__ u16 f2b(float f) {
  union { float f; unsigned i; } t; t.f = f;
  unsigned r = t.i + 0x7fffu + ((t.i >> 16) & 1u);
  return (u16)(r >> 16);
}
static __device__ __forceinline__ ushort4 pk4(float4 v) {
  return make_ushort4(f2b(v.x), f2b(v.y), f2b(v.z), f2b(v.w));
}
static __device__ __forceinline__ void gload16(const void* g, void* l) {
  __builtin_amdgcn_global_load_lds((const __attribute__((address_space(1))) void*)g,
                                   (__attribute__((address_space(3))) void*)l, 16, 0, 0);
}

// ---------------- fused preamble --------------------------------------------------
// ranges: [0,24576) ln_qkv | [24576,25600) cvtw (W3 pre-multiplied by ln_o gamma)
//         [25600,25728) rope | [25728,26752) c1/c2b per-output-col LN-fold constants
__global__ __launch_bounds__(256) void prep(
    const float4* __restrict__ q, const float4* __restrict__ k, const float4* __restrict__ v,
    const float* __restrict__ g0, const float* __restrict__ b0,
    const float* __restrict__ g1, const float* __restrict__ b1,
    const float* __restrict__ g2, const float* __restrict__ b2,
    ushort4* __restrict__ o0, ushort4* __restrict__ o1, ushort4* __restrict__ o2,
    const float4* __restrict__ w0, const float4* __restrict__ w1,
    const float4* __restrict__ w2, const float4* __restrict__ w3,
    ushort4* __restrict__ wout,
    float* __restrict__ ropc, float* __restrict__ rops,
    const float* __restrict__ g3, const float* __restrict__ b3,
    const float* __restrict__ bias_o,
    float* __restrict__ c1, float* __restrict__ c2b) {
  __shared__ float ps[8];
  const int bid = blockIdx.x, tid = threadIdx.x;
  const int lane = tid & 63, wave = tid >> 6;
  if (bid < 24576) {  // ---- ln_qkv
    const int row = bid & 8191, sel = bid >> 13;
    const float4* src = (sel == 0) ? q : (sel == 1) ? k : v;
    const float* gam = (sel == 0) ? g0 : (sel == 1) ? g1 : g2;
    const float* bet = (sel == 0) ? b0 : (sel == 1) ? b1 : b2;
    ushort4* dst = (sel == 0) ? o0 : (sel == 1) ? o1 : o2;

    float4 v4 = src[(size_t)row * 256 + tid];
    float s = v4.x + v4.y + v4.z + v4.w;
    float s2 = v4.x * v4.x + v4.y * v4.y + v4.z * v4.z + v4.w * v4.w;
#pragma unroll
    for (int d = 1; d < 64; d <<= 1) { s += __shfl_xor(s, d); s2 += __shfl_xor(s2, d); }
    if (lane == 0) { ps[wave] = s; ps[4 + wave] = s2; }
    __syncthreads();
    float tot = ps[0] + ps[1] + ps[2] + ps[3];
    float tot2 = ps[4] + ps[5] + ps[6] + ps[7];
    float mean = tot * (1.f / 1024.f);
    float var = tot2 * (1.f / 1024.f) - mean * mean;
    float rstd = rsqrtf(var + 1e-5f);
    float4 gv = ((const float4*)gam)[tid];
    float4 bv = ((const float4*)bet)[tid];
    dst[(size_t)row * 256 + tid] = make_ushort4(
        f2b((v4.x - mean) * rstd * gv.x + bv.x), f2b((v4.y - mean) * rstd * gv.y + bv.y),
        f2b((v4.z - mean) * rstd * gv.z + bv.z), f2b((v4.w - mean) * rstd * gv.w + bv.w));
  } else if (bid < 25600) {  // ---- cvtw (W3 folded with ln_o gamma)
    int i = (bid - 24576) * 256 + tid;  // 0..262143 float4 units
    wout[i]          = pk4(w0[i]);
    wout[i + 262144] = pk4(w1[i]);
    wout[i + 524288] = pk4(w2[i]);
    float4 wv = w3[i];
    float4 g4 = ((const float4*)g3)[i & 255];
    wv.x *= g4.x; wv.y *= g4.y; wv.z *= g4.z; wv.w *= g4.w;
    wout[i + 786432] = pk4(wv);
  } else if (bid < 25728) {  // ---- rope tables: 512 positions x 64 dims
    int idx = (bid - 25600) * 256 + tid;  // 0..32767
    int p = idx >> 6, d = idx & 63;
    int t2 = d & ~1;
    double inv = pow(10000.0, -(double)t2 / 64.0);
    double f = (double)p * inv;
    ropc[idx] = (float)cos(f);
    rops[idx] = (float)sin(f);
  } else {  // ---- LN-fold constants: c1[n]=sum g3[k]W3[n,k]; c2b[n]=sum b3[k]W3[n,k]+bias_o[n]
    int n = bid - 25728;
    float4 wv = w3[n * 256 + tid];
    float4 gv = ((const float4*)g3)[tid];
    float4 bv = ((const float4*)b3)[tid];
    float s1 = wv.x * gv.x + wv.y * gv.y + wv.z * gv.z + wv.w * gv.w;
    float s2 = wv.x * bv.x + wv.y * bv.y + wv.z * bv.z + wv.w * bv.w;
#pragma unroll
    for (int d = 1; d < 64; d <<= 1) { s1 += __shfl_xor(s1, d); s2 += __shfl_xor(s2, d); }
    if (lane == 0) { ps[wave] = s1; ps[4 + wave] = s2; }
    __syncthreads();
    if (tid == 0) {
      c1[n] = ps[0] + ps[1] + ps[2] + ps[3];
      c2b[n] = ps[4] + ps[5] + ps[6] + ps[7] + bias_o[n];
    }
  }
}

// ---------------- per-row mean/rstd of attn output (for folded LN) ----------------
__global__ __launch_bounds__(256) void ostats(const ushort4* __restrict__ xin,
                                              float* __restrict__ mean,
                                              float* __restrict__ rstd) {
  __shared__ float ps[8];
  int row = blockIdx.x, tid = threadIdx.x;
  int lane = tid & 63, wave = tid >> 6;
  ushort4 u = xin[(size_t)row * 256 + tid];
  float x = b2f(u.x), y = b2f(u.y), z = b2f(u.z), w = b2f(u.w);
  float s = x + y + z + w;
  float s2 = x * x + y * y + z * z + w * w;
#pragma unroll
  for (int d = 1; d < 64; d <<= 1) { s += __shfl_xor(s, d); s2 += __shfl_xor(s2, d); }
  if (lane == 0) { ps[wave] = s; ps[4 + wave] = s2; }
  __syncthreads();
  if (tid == 0) {
    float tot = ps[0] + ps[1] + ps[2] + ps[3];
    float tot2 = ps[4] + ps[5] + ps[6] + ps[7];
    float m = tot * (1.f / 1024.f);
    float var = tot2 * (1.f / 1024.f) - m * m;
    mean[row] = m;
    rstd[row] = rsqrtf(var + 1e-5f);
  }
}

// ---------------- fused QKV NT GEMM (blockIdx.y = mode 0/1/2) ---------------------
__global__ __launch_bounds__(256, 3) void gemm_qkv(
    const u16* __restrict__ Aq, const u16* __restrict__ Ak, const u16* __restrict__ Av,
    const u16* __restrict__ wbf,
    const float* __restrict__ bq, const float* __restrict__ bk, const float* __restrict__ bv,
    const float* __restrict__ ropc, const float* __restrict__ rops,
    u16* __restrict__ qrot, u16* __restrict__ krot, u16* __restrict__ vTp) {
  __shared__ __align__(16) char smem[34816];  // staging 32KB; epilogue C-tile 128x136 u16
  u16* Als = (u16*)smem;
  u16* Bls = (u16*)(smem + 16384);
  const int tid = threadIdx.x, lane = tid & 63, wave = tid >> 6;
  const int g = lane >> 4, ln15 = lane & 15;
  const int mode = blockIdx.y;
  const u16* A = (mode == 0) ? Aq : (mode == 1) ? Ak : Av;
  const u16* Bw = wbf + (size_t)mode * 1048576;
  const float* bias = (mode == 0) ? bq : (mode == 1) ? bk : bv;
  const int bid = blockIdx.x;
  const int xcd = bid & 7, idx = bid >> 3;
  const int row0 = (xcd * 8 + (idx >> 3)) * 128;
  const int col0 = (idx & 7) * 128;
  const int wm = (wave >> 1) * 64, wn = (wave & 1) * 64;
  const int K = 1024;
  f32x4 acc[4][4] = {};

  for (int k0 = 0; k0 < K; k0 += 64) {
#pragma unroll
    for (int i = 0; i < 4; ++i) {  // A tile: 16KB, swizzled via pre-swizzled source
      int ch = i * 4 + wave;
      int olin = ch * 1024 + lane * 16;
      int r = olin >> 7;
      int cel = ((olin ^ ((r & 7) << 4)) >> 1) & 63;
      gload16(A + (size_t)(row0 + r) * K + k0 + cel, (char*)Als + ch * 1024);
    }
#pragma unroll
    for (int i = 0; i < 4; ++i) {  // B tile
      int ch = i * 4 + wave;
      int olin = ch * 1024 + lane * 16;
      int r = olin >> 7;
      int cel = ((olin ^ ((r & 7) << 4)) >> 1) & 63;
      gload16(Bw + (size_t)(col0 + r) * K + k0 + cel, (char*)Bls + ch * 1024);
    }
    __syncthreads();
#pragma unroll
    for (int ks = 0; ks < 2; ++ks) {
      bf16x8 af[4], bfv[4];
      int cb = (ks * 32 + g * 8) * 2;
#pragma unroll
      for (int mi = 0; mi < 4; ++mi) {
        int r = wm + mi * 16 + ln15;
        af[mi] = *(const bf16x8*)((const char*)Als + r * 128 + (cb ^ ((r & 7) << 4)));
      }
#pragma unroll
      for (int ni = 0; ni < 4; ++ni) {
        int r = wn + ni * 16 + ln15;
        bfv[ni] = *(const bf16x8*)((const char*)Bls + r * 128 + (cb ^ ((r & 7) << 4)));
      }
#pragma unroll
      for (int mi = 0; mi < 4; ++mi)
#pragma unroll
        for (int ni = 0; ni < 4; ++ni)
          acc[mi][ni] = MFMA16(af[mi], bfv[ni], acc[mi][ni]);
    }
    __syncthreads();
  }

  // ---- epilogue: rotary (f32, single rounding) + LDS-staged coalesced writes ----
  u16* Cl = (u16*)smem;  // 128 x 136 u16 (stride 272B)
#pragma unroll
  for (int mi = 0; mi < 4; ++mi)
#pragma unroll
    for (int ni = 0; ni < 4; ++ni)
#pragma unroll
      for (int r = 0; r < 4; ++r) {
        int rowc = wm + mi * 16 + g * 4 + r;
        int colc = wn + ni * 16 + ln15;
        int row = row0 + rowc, col = col0 + colc;
        float val = acc[mi][ni][r] + bias[col];
        if (mode == 2) {
          Cl[colc * 136 + rowc] = f2b(val);  // transposed store for (B,H,d,L) out
        } else {
          if (mode == 0) val *= 0.125f;      // fold 1/sqrt(hd) into Q
          float oth = __shfl_xor(val, 1);    // rotary partner (adjacent dim = adjacent lane)
          int d = col & 63;
          int pp = (row & 255) + ((mode == 1) ? 256 : 0);
          float cc = ropc[pp * 64 + d], ss = rops[pp * 64 + d];
          Cl[rowc * 136 + colc] = f2b((d & 1) ? (val * cc + oth * ss) : (val * cc - oth * ss));
        }
      }
  __syncthreads();
  if (mode == 2) {
#pragma unroll
    for (int i = 0; i < 8; ++i) {
      int c2 = i * 256 + tid;
      int dloc = c2 >> 4, lgrp = c2 & 15;
      bf16x8 vv = *(const bf16x8*)(Cl + dloc * 136 + lgrp * 8);
      int colg = col0 + dloc, hh = colg >> 6, d = colg & 63;
      int l = row0 + lgrp * 8, bb = l >> 12, ll = l & 4095;
      *(bf16x8*)(vTp + (((size_t)bb * HEADS + hh) * HD + d) * LSEQ + ll) = vv;
    }
  } else {
    u16* dst = (mode == 0) ? qrot : krot;
#pragma unroll
    for (int i = 0; i < 8; ++i) {
      int c2 = i * 256 + tid;
      int rowc = c2 >> 4, cgrp = c2 & 15;
      bf16x8 vv = *(const bf16x8*)(Cl + rowc * 136 + cgrp * 8);
      int l = row0 + rowc, bb = l >> 12, ll = l & 4095;
      int colg = col0 + cgrp * 8, hh = colg >> 6, d0 = colg & 63;
      *(bf16x8*)(dst + (((size_t)bb * HEADS + hh) * LSEQ + ll) * HD + d0) = vv;
    }
  }
}

// ---------------- final NT GEMM with folded LayerNorm -----------------------------
// out[r,n] = rstd[r]*(obuf @ (g∘Wo)^T)[r,n] - rstd[r]*mean[r]*c1[n] + c2b[n]
__global__ __launch_bounds__(256, 3) void gemm_o(
    const u16* __restrict__ A, const u16* __restrict__ Bw,
    const float* __restrict__ mean, const float* __restrict__ rstd,
    const float* __restrict__ c1, const float* __restrict__ c2b,
    float* __restrict__ outf) {
  __shared__ __align__(16) u16 Als[128 * 64];
  __shared__ __align__(16) u16 Bls[128 * 64];
  const int tid = threadIdx.x, lane = tid & 63, wave = tid >> 6;
  const int g = lane >> 4, ln15 = lane & 15;
  const int bid = blockIdx.x;
  const int xcd = bid & 7, idx = bid >> 3;
  const int row0 = (xcd * 8 + (idx >> 3)) * 128;
  const int col0 = (idx & 7) * 128;
  const int wm = (wave >> 1) * 64, wn = (wave & 1) * 64;
  const int K = 1024, N = 1024;
  f32x4 acc[4][4] = {};

  for (int k0 = 0; k0 < K; k0 += 64) {
#pragma unroll
    for (int i = 0; i < 4; ++i) {
      int ch = i * 4 + wave;
      int olin = ch * 1024 + lane * 16;
      int r = olin >> 7;
      int cel = ((olin ^ ((r & 7) << 4)) >> 1) & 63;
      gload16(A + (size_t)(row0 + r) * K + k0 + cel, (char*)Als + ch * 1024);
    }
#pragma unroll
    for (int i = 0; i < 4; ++i) {
      int ch = i * 4 + wave;
      int olin = ch * 1024 + lane * 16;
      int r = olin >> 7;
      int cel = ((olin ^ ((r & 7) << 4)) >> 1) & 63;
      gload16(Bw + (size_t)(col0 + r) * K + k0 + cel, (char*)Bls + ch * 1024);
    }
    __syncthreads();
#pragma unroll
    for (int ks = 0; ks < 2; ++ks) {
      bf16x8 af[4], bfv[4];
      int cb = (ks * 32 + g * 8) * 2;
#pragma unroll
      for (int mi = 0; mi < 4; ++mi) {
        int r = wm + mi * 16 + ln15;
        af[mi] = *(const bf16x8*)((const char*)Als + r * 128 + (cb ^ ((r & 7) << 4)));
      }
#pragma unroll
      for (int ni = 0; ni < 4; ++ni) {
        int r = wn + ni * 16 + ln15;
        bfv[ni] = *(const bf16x8*)((const char*)Bls + r * 128 + (cb ^ ((r & 7) << 4)));
      }
#pragma unroll
      for (int mi = 0; mi < 4; ++mi)
#pragma unroll
        for (int ni = 0; ni < 4; ++ni)
          acc[mi][ni] = MFMA16(af[mi], bfv[ni], acc[mi][ni]);
    }
    __syncthreads();
  }

#pragma unroll
  for (int mi = 0; mi < 4; ++mi)
#pragma unroll
    for (int r = 0; r < 4; ++r) {
      int row = row0 + wm + mi * 16 + g * 4 + r;
      float rho = rstd[row];
      float rm = rho * mean[row];
#pragma unroll
      for (int ni = 0; ni < 4; ++ni) {
        int col = col0 + wn + ni * 16 + ln15;
        outf[(size_t)row * N + col] = rho * acc[mi][ni][r] - rm * c1[col] + c2b[col];
      }
    }
}

// ---------------- fused windowed attention (v8: V-load hoist) ---------------------
// block = (b, h, bucket); 8 waves x 32 q-rows; K staged 128 cols/stage, dbuf.
// V fragment loads hoisted to chunk start so QK^T MFMAs + softmax VALU hide their
// global latency. krot holds R(256+p)k; prev-bucket chunks use q~ = R(256)*qrot.
__global__ __launch_bounds__(512, 2) void attn_kernel(
    const u16* __restrict__ qrot,   // (B,H,L,64) rotated by R(l%256), scaled 0.125
    const u16* __restrict__ krot,   // (B,H,L,64) rotated by R(256+l%256)
    const u16* __restrict__ vT,     // (B,H,64,L)
    const int* __restrict__ cell,   // (B,L)
    const float* __restrict__ ropc, const float* __restrict__ rops,
    u16* __restrict__ o) {          // (B,L,1024) bf16
  __shared__ __align__(16) u16 Kc[2][128 * 64];  // dbuf K stages, swizzled, 2x16KB
  __shared__ __align__(16) u16 Pl[8 * 32 * 64];  // per-wave P relay, swizzled, 32KB
  __shared__ int ci[256];
  __shared__ int cj[512];

  const int tid = threadIdx.x, lane = tid & 63, wave = tid >> 6;
  const int g = lane >> 4, ln15 = lane & 15;
  const int bucket = blockIdx.x & 15;
  const int h = (blockIdx.x >> 4) & 15;
  const int b = blockIdx.x >> 8;
  const int w0 = bucket * 256;
  const size_t base = (size_t)(b * HEADS + h) * LSEQ * HD;

  if (tid < 256) ci[tid] = cell[b * LSEQ + w0 + tid];
  {
    int gj = w0 - 256 + tid;
    cj[tid] = (gj >= 0) ? cell[b * LSEQ + gj] : (int)0x80000000;
  }

  // Q fragments (already rotated + scaled): rows w0 + wave*32 + mi*16 + ln15
  bf16x8 qf[2][2];
#pragma unroll
  for (int mi = 0; mi < 2; ++mi)
#pragma unroll
    for (int ks = 0; ks < 2; ++ks)
      qf[mi][ks] = *(const bf16x8*)(qrot + base +
          (size_t)(w0 + wave * 32 + mi * 16 + ln15) * HD + ks * 32 + g * 8);

  // prev-view Q: q~ = R(256) * qf (fixed-angle in-register rotation, once per block)
  bf16x8 qfB[2][2];
#pragma unroll
  for (int ks = 0; ks < 2; ++ks) {
    const int d0 = ks * 32 + g * 8;
    float rc[8], rs8[8];
#pragma unroll
    for (int j = 0; j < 8; ++j) {
      rc[j] = ropc[256 * 64 + d0 + j];
      rs8[j] = rops[256 * 64 + d0 + j];
    }
#pragma unroll
    for (int mi = 0; mi < 2; ++mi) {
      bf16x8 s = qf[mi][ks], t;
#pragma unroll
      for (int j = 0; j < 8; j += 2) {
        float e = b2f((u16)s[j]), od = b2f((u16)s[j + 1]);
        t[j]     = (short)f2b(e * rc[j] - od * rs8[j]);
        t[j + 1] = (short)f2b(e * rs8[j] + od * rc[j]);
      }
      qfB[mi][ks] = t;
    }
  }

  f32x4 Oa[2][4] = {};
  float mrow[2][4], lrow[2][4];
#pragma unroll
  for (int a1 = 0; a1 < 2; ++a1)
#pragma unroll
    for (int a2 = 0; a2 < 4; ++a2) { mrow[a1][a2] = NEGF; lrow[a1][a2] = 0.f; }

#define STAGE_K(bi, s)                                                          \
  {                                                                             \
    int gj0_ = w0 - 256 + (s) * 128;                                            \
    _Pragma("unroll")                                                           \
    for (int i_ = 0; i_ < 2; ++i_) {                                            \
      int ch_ = i_ * 8 + wave;                                                  \
      int olin_ = ch_ * 1024 + lane * 16;                                       \
      int r_ = olin_ >> 7;                                                      \
      int cel_ = ((olin_ ^ ((r_ & 7) << 4)) >> 1) & 63;                         \
      gload16(krot + base + (size_t)(gj0_ + r_) * HD + cel_,                    \
              (char*)Kc[bi] + ch_ * 1024);                                      \
    }                                                                           \
  }

  const int s0 = (bucket == 0) ? 2 : 0;
  STAGE_K(0, s0);
  __syncthreads();  // stage s0 ready; ci/cj visible

  // cell intervals (sorted): block rows, this wave's rows
  const int crb_lo = ci[0], crb_hi = ci[255];
  const int crw_lo = ci[wave * 32], crw_hi = ci[wave * 32 + 31];

  for (int s = s0; s < 4; ++s) {
    const int cur = (s - s0) & 1;
    if (s + 1 < 4) {
      // block-level staging skip
      int k1 = (s + 1) * 2;
      bool need = false;
#pragma unroll
      for (int kk = 0; kk < 2; ++kk) {
        int clo = cj[(k1 + kk) * 64], chi = cj[(k1 + kk) * 64 + 63];
        need = need || !(chi < crb_lo || clo > crb_hi);
      }
      if (need) STAGE_K(cur ^ 1, s + 1);
    }

    // two 64-col sub-chunks within this stage
#pragma unroll
    for (int sub = 0; sub < 2; ++sub) {
      const int k = s * 2 + sub;                   // 64-col chunk index 0..7
      if (k * 64 > wave * 32 + 287) continue;      // causal: no col in chunk reachable
      {                                            // cell-interval skip (exact)
        int clo = cj[k * 64], chi = cj[k * 64 + 63];
        if (chi < crw_lo || clo > crw_hi) continue;
      }
      const int gj0 = w0 - 256 + k * 64;           // global col base of chunk
      const int lr0 = sub * 64;                    // local row base in Kc stage
      const bool prevhalf = (k < 4);

      // ---- V fragments hoisted: issued here, consumed after softmax (latency hidden)
      bf16x8 vb[2][4];
#pragma unroll
      for (int jb = 0; jb < 2; ++jb)
#pragma unroll
        for (int nd = 0; nd < 4; ++nd) {
          int d = nd * 16 + ln15;
          int p0 = gj0 + jb * 32 + g * 8;
          vb[jb][nd] = *(const bf16x8*)(vT + base + (size_t)d * LSEQ + p0);
        }

#pragma unroll
      for (int mi = 0; mi < 2; ++mi) {
        f32x4 sc[4] = {};
        __builtin_amdgcn_s_setprio(1);
#pragma unroll
        for (int ks = 0; ks < 2; ++ks) {
          int cb = (ks * 32 + g * 8) * 2;
          bf16x8 aq = prevhalf ? qfB[mi][ks] : qf[mi][ks];
#pragma unroll
          for (int ni = 0; ni < 4; ++ni) {
            int r = lr0 + ni * 16 + ln15;
            bf16x8 kf = *(const bf16x8*)((const char*)Kc[cur] + r * 128 + (cb ^ ((r & 7) << 4)));
            sc[ni] = MFMA16(aq, kf, sc[ni]);
          }
        }
        __builtin_amdgcn_s_setprio(0);
        // mask + row max (scores pre-scaled via Q)
        float mx[4] = {NEGF, NEGF, NEGF, NEGF};
#pragma unroll
        for (int ni = 0; ni < 4; ++ni)
#pragma unroll
          for (int r = 0; r < 4; ++r) {
            int iloc = wave * 32 + mi * 16 + g * 4 + r;
            int p = k * 64 + ni * 16 + ln15;
            bool ok = (p <= iloc + 256) && (ci[iloc] == cj[p]);
            float sv = ok ? sc[ni][r] : NEGF;
            sc[ni][r] = sv;
            mx[r] = fmaxf(mx[r], sv);
          }
#pragma unroll
        for (int d = 1; d < 16; d <<= 1)
#pragma unroll
          for (int r = 0; r < 4; ++r) mx[r] = fmaxf(mx[r], __shfl_xor(mx[r], d));
        float rs[4] = {0.f, 0.f, 0.f, 0.f};
        // T13 defer-max: rescale only if max grew by > 8
        bool big = false;
#pragma unroll
        for (int r = 0; r < 4; ++r) big = big || (mx[r] > mrow[mi][r] + 8.0f);
        if (__any(big)) {
#pragma unroll
          for (int r = 0; r < 4; ++r) {
            float mold = mrow[mi][r];
            float mnew = fmaxf(mold, mx[r]);
            float alpha = __expf(mold - mnew);  // NEG,NEG -> 1; NEG,finite -> 0
            mrow[mi][r] = mnew;
            lrow[mi][r] *= alpha;
#pragma unroll
            for (int nd = 0; nd < 4; ++nd) Oa[mi][nd][r] *= alpha;
          }
        }
#pragma unroll
        for (int ni = 0; ni < 4; ++ni)
#pragma unroll
          for (int r = 0; r < 4; ++r) {
            float sv = sc[ni][r];
            float p = (sv > NEGF * 0.5f) ? __expf(sv - mrow[mi][r]) : 0.f;
            rs[r] += p;
            int row = mi * 16 + g * 4 + r;
            int colb = (ni * 16 + ln15) * 2;
            *(u16*)((char*)Pl + wave * 4096 + row * 128 + (colb ^ ((row & 7) << 4))) = f2b(p);
          }
#pragma unroll
        for (int d = 1; d < 16; d <<= 1)
#pragma unroll
          for (int r = 0; r < 4; ++r) rs[r] += __shfl_xor(rs[r], d);
#pragma unroll
        for (int r = 0; r < 4; ++r) lrow[mi][r] += rs[r];
      }  // mi

      // PV: O += P(32x64) * V(64x64); V already in registers
#pragma unroll
      for (int jb = 0; jb < 2; ++jb) {
        bf16x8 pa[2];
        int cb = (jb * 32 + g * 8) * 2;
#pragma unroll
        for (int mi = 0; mi < 2; ++mi) {
          int row = mi * 16 + ln15;
          pa[mi] = *(const bf16x8*)((const char*)Pl + wave * 4096 + row * 128 + (cb ^ ((row & 7) << 4)));
        }
        __builtin_amdgcn_s_setprio(1);
#pragma unroll
        for (int mi = 0; mi < 2; ++mi)
#pragma unroll
          for (int nd = 0; nd < 4; ++nd) Oa[mi][nd] = MFMA16(pa[mi], vb[jb][nd], Oa[mi][nd]);
        __builtin_amdgcn_s_setprio(0);
      }
    }  // sub

    __syncthreads();  // stage s+1 writes complete + all readers of Kc[cur] done
  }  // stages

  // epilogue: normalize and store
#pragma unroll
  for (int mi = 0; mi < 2; ++mi)
#pragma unroll
    for (int r = 0; r < 4; ++r) {
      float invl = 1.0f / lrow[mi][r];
      int gi = w0 + wave * 32 + mi * 16 + g * 4 + r;
      size_t ob = ((size_t)b * LSEQ + gi) * DM + h * HD;
#pragma unroll
      for (int nd = 0; nd < 4; ++nd) o[ob + nd * 16 + ln15] = f2b(Oa[mi][nd][r] * invl);
    }
#undef STAGE_K
}

extern "C" void kernel_launch(void* const* d_in, const int* in_sizes, int n_in,
                              void* d_out, int out_size, void* d_ws, size_t ws_size,
                              hipStream_t stream) {
  const float* q = (const float*)d_in[0];
  const float* k = (const float*)d_in[1];
  const float* v = (const float*)d_in[2];
  const int* cell = (const int*)d_in[3];
  const float* lnw[4] = {(const float*)d_in[4], (const float*)d_in[8], (const float*)d_in[12], (const float*)d_in[16]};
  const float* lnb[4] = {(const float*)d_in[5], (const float*)d_in[9], (const float*)d_in[13], (const float*)d_in[17]};
  const float* Wm[4]  = {(const float*)d_in[6], (const float*)d_in[10], (const float*)d_in[14], (const float*)d_in[18]};
  const float* bi[4]  = {(const float*)d_in[7], (const float*)d_in[11], (const float*)d_in[15], (const float*)d_in[19]};

  char* ws = (char*)d_ws;
  u16* xlnq  = (u16*)(ws);               // 16 MiB: LN'd q
  u16* wbf   = (u16*)(ws + 16777216);    // 8 MiB: 4 bf16 weights (W3 gamma-folded)
  u16* qrot  = (u16*)(ws + 25165824);    // 16 MiB
  u16* krot  = (u16*)(ws + 41943040);    // 16 MiB (single K view)
  float* omean = (float*)(ws + 58720256);   // 32 KB (old krB slot, free)
  float* orstd = (float*)(ws + 58753024);   // 32 KB
  float* c1    = (float*)(ws + 58785792);   // 4 KB
  float* c2b   = (float*)(ws + 58789888);   // 4 KB
  u16* vT    = (u16*)(ws + 75497472);    // 16 MiB
  u16* obuf  = (u16*)(ws + 92274688);    // 16 MiB: xln_k, then attn output
  float* ropc = (float*)(ws + 109051904);
  float* rops = (float*)(ws + 109182976);
  u16* xlnk = obuf;                      // alias: free until attn writes
  u16* xlnv = (u16*)d_out;               // scratch in d_out (fully overwritten by gemm_o)

  prep<<<26752, 256, 0, stream>>>(
      (const float4*)q, (const float4*)k, (const float4*)v,
      lnw[0], lnb[0], lnw[1], lnb[1], lnw[2], lnb[2],
      (ushort4*)xlnq, (ushort4*)xlnk, (ushort4*)xlnv,
      (const float4*)Wm[0], (const float4*)Wm[1], (const float4*)Wm[2], (const float4*)Wm[3],
      (ushort4*)wbf, ropc, rops,
      lnw[3], lnb[3], bi[3], c1, c2b);

  dim3 gq(512, 3);
  gemm_qkv<<<gq, 256, 0, stream>>>(xlnq, xlnk, xlnv, wbf, bi[0], bi[1], bi[2],
                                   ropc, rops, qrot, krot, vT);
  attn_kernel<<<512, 512, 0, stream>>>(qrot, krot, vT, cell, ropc, rops, obuf);
  ostats<<<8192, 256, 0, stream>>>((const ushort4*)obuf, omean, orstd);
  gemm_o<<<512, 256, 0, stream>>>(obuf, wbf + 3145728, omean, orstd, c1, c2b, (float*)d_out);
}